// Round 4
// baseline (410.882 us; speedup 1.0000x reference)
//
#include <hip/hip_runtime.h>
#include <stdint.h>

#define H_ 192
#define W_ 192
#define C_ 64
#define EPS_F 1e-8f
#define TILE 16
#define RCH 256      // raster chunk size (faces)
#define NS 2         // z-interleaved slices per tile
#define NBUCK 256
#define MAXCH 65     // max chunks + 1  (16384/256 = 64)

typedef unsigned long long ull;

// Output layout (floats), concatenated in reference return order:
// feats (H*W*C) | p2f (H*W) | zbuf (H*W) | bary (H*W*3) | dists (H*W)
#define OFF_FEATS 0
#define OFF_P2F   (H_*W_*C_)
#define OFF_ZBUF  (OFF_P2F + H_*W_)
#define OFF_BARY  (OFF_ZBUF + H_*W_)
#define OFF_DIST  (OFF_BARY + H_*W_*3)

// IEEE-exact ops (block FMA contraction; match numpy float32 op-for-op)
__device__ __forceinline__ float xm(float a, float b){ return __fmul_rn(a,b); }
__device__ __forceinline__ float xa(float a, float b){ return __fadd_rn(a,b); }
__device__ __forceinline__ float xsb(float a, float b){ return __fsub_rn(a,b); }
__device__ __forceinline__ float xd(float a, float b){ return __fdiv_rn(a,b); }

__device__ __forceinline__ float pixcoord(int i, float dim){
    float t = xa(xm(2.0f, (float)i), 1.0f);
    return xsb(1.0f, xd(t, dim));
}

__device__ __forceinline__ int zbucket(float zmn){
    int b = (int)((zmn - 2.5f) * 128.0f);   // [2.5,4.5] -> [0,256); clamp keeps soundness
    return max(0, min(NBUCK-1, b));
}

// ---- kernel 1: keys init + histogram zero + vertex transform ----
__global__ void k_init(const float* __restrict__ pos, const float* __restrict__ K,
                       const float* __restrict__ RT, float* __restrict__ verts,
                       ull* __restrict__ keys, int* __restrict__ hist, int V){
    int i = blockIdx.x*blockDim.x + threadIdx.x;
    if (i < NBUCK) hist[i] = 0;
    if (i < H_*W_) keys[i] = 0xFFFFFFFFFFFFFFFFULL;
    if (i >= V) return;
    float p0 = pos[3*i+0], p1 = pos[3*i+1], p2 = pos[3*i+2];
    const float sgn[3] = {-1.f, -1.f, 1.f};
    float vv[3];
    #pragma unroll
    for (int j=0;j<3;j++){
        float rp0 = xm(RT[j*4+0], sgn[j]);
        float rp1 = xm(RT[j*4+1], sgn[j]);
        float rp2 = xm(RT[j*4+2], sgn[j]);
        float s = xa(xa(xm(p0,rp0), xm(p1,rp1)), xm(p2,rp2));
        vv[j] = xa(s, xm(RT[j*4+3], sgn[j]));
    }
    float z = vv[2];
    const float scale = 96.0f;
    float fx = xd(K[0], scale);
    float fy = xd(K[4], scale);
    float p0x = -xd(xsb(K[2], 96.0f), scale);
    float p0y = -xd(xsb(K[5], 96.0f), scale);
    float xn = xa(xd(xm(fx, vv[0]), z), p0x);
    float yn = xa(xd(xm(fy, vv[1]), z), p0y);
    verts[4*i+0] = xn; verts[4*i+1] = yn; verts[4*i+2] = z; verts[4*i+3] = 0.f;
}

// ---- kernel 2: live-face zmin histogram (LDS-aggregated) ----
__global__ __launch_bounds__(256) void k_hist(const int* __restrict__ faces,
        const float* __restrict__ verts, int* __restrict__ hist, int Fn){
    __shared__ int lh[NBUCK];
    int t = threadIdx.x;
    lh[t] = 0;
    __syncthreads();
    int f = blockIdx.x*256 + t;
    if (f < Fn){
        int i0 = faces[3*f+0], i1 = faces[3*f+1], i2 = faces[3*f+2];
        float4 v0 = ((const float4*)verts)[i0];
        float4 v1 = ((const float4*)verts)[i1];
        float4 v2 = ((const float4*)verts)[i2];
        float area = xsb(xm(xsb(v1.x,v0.x), xsb(v2.y,v0.y)), xm(xsb(v1.y,v0.y), xsb(v2.x,v0.x)));
        bool ok = (area > EPS_F) && (v0.z > 0.f) && (v1.z > 0.f) && (v2.z > 0.f);
        if (ok){
            float zmn = fminf(v0.z, fminf(v1.z, v2.z));
            atomicAdd(&lh[zbucket(zmn)], 1);
        }
    }
    __syncthreads();
    if (lh[t]) atomicAdd(&hist[t], lh[t]);
}

// ---- kernel 3: exclusive prefix of histogram -> bucket cursors + total ----
__global__ __launch_bounds__(256) void k_prefix(const int* __restrict__ hist,
        int* __restrict__ cursor, int* __restrict__ cnt){
    __shared__ int tmp[NBUCK];
    int t = threadIdx.x;
    int h = hist[t];
    tmp[t] = h;
    __syncthreads();
    for (int off=1; off<NBUCK; off<<=1){
        int u = (t >= off) ? tmp[t-off] : 0;
        __syncthreads();
        tmp[t] += u;
        __syncthreads();
    }
    cursor[t] = tmp[t] - h;    // exclusive
    if (t == NBUCK-1) *cnt = tmp[NBUCK-1];
}

// ---- kernel 4: scatter live faces into z-bucket-sorted record array ----
// record (16 floats): x0,y0,x1,y1 | x2,y2,z0,z1 | z2,ia,zmin,fidx(bits) | xmn,xmx,ymn,ymx
__global__ __launch_bounds__(256) void k_scatter(const int* __restrict__ faces,
        const float* __restrict__ verts, int* __restrict__ cursor,
        float* __restrict__ srec, int Fn){
    int f = blockIdx.x*256 + threadIdx.x;
    if (f >= Fn) return;
    int i0 = faces[3*f+0], i1 = faces[3*f+1], i2 = faces[3*f+2];
    float4 v0 = ((const float4*)verts)[i0];
    float4 v1 = ((const float4*)verts)[i1];
    float4 v2 = ((const float4*)verts)[i2];
    float area = xsb(xm(xsb(v1.x,v0.x), xsb(v2.y,v0.y)), xm(xsb(v1.y,v0.y), xsb(v2.x,v0.x)));
    bool ok = (area > EPS_F) && (v0.z > 0.f) && (v1.z > 0.f) && (v2.z > 0.f);
    if (!ok) return;
    float zmn = fminf(v0.z, fminf(v1.z, v2.z));
    int pos = atomicAdd(&cursor[zbucket(zmn)], 1);
    float ia = xd(1.0f, area);
    float xmn = fminf(v0.x, fminf(v1.x, v2.x)) - 1e-4f;
    float xmx = fmaxf(v0.x, fmaxf(v1.x, v2.x)) + 1e-4f;
    float ymn = fminf(v0.y, fminf(v1.y, v2.y)) - 1e-4f;
    float ymx = fmaxf(v0.y, fmaxf(v1.y, v2.y)) + 1e-4f;
    float4* q = (float4*)(srec + (size_t)pos*16);
    q[0] = make_float4(v0.x, v0.y, v1.x, v1.y);
    q[1] = make_float4(v2.x, v2.y, v0.z, v1.z);
    q[2] = make_float4(v2.z, ia, zmn, __int_as_float(f));
    q[3] = make_float4(xmn, xmx, ymn, ymx);
}

// ---- kernel 5: exact per-chunk suffix-min of zmin over sorted array ----
__global__ __launch_bounds__(256) void k_sufmin(const float* __restrict__ srec,
        const int* __restrict__ cnt, float* __restrict__ sufchunk){
    __shared__ float cm[MAXCH];
    int t = threadIdx.x;
    int alive = *cnt;
    int nch = (alive + RCH-1) >> 8;
    if (t < MAXCH){
        float m = INFINITY;
        if (t < nch){
            int i0 = t << 8, i1 = min(i0 + RCH, alive);
            for (int i = i0; i < i1; i++) m = fminf(m, srec[(size_t)i*16 + 10]);
        }
        cm[t] = m;
    }
    __syncthreads();
    if (t == 0){
        float run = INFINITY;
        for (int c = MAXCH-1; c >= 0; c--){ run = fminf(run, cm[c]); sufchunk[c] = run; }
    }
}

// ---- kernel 6: z-ordered tiled raster with early termination ----
__global__ __launch_bounds__(256) void k_raster(const float* __restrict__ srec,
        const int* __restrict__ cnt, const float* __restrict__ sufchunk,
        ull* __restrict__ keys){
    __shared__ float lf[RCH*16];
    __shared__ int wcnt[4];
    int tid = threadIdx.x;
    int ix = blockIdx.x*TILE + (tid & 15);
    int iy = blockIdx.y*TILE + (tid >> 4);
    int pix = iy*W_ + ix;
    float px = pixcoord(ix, (float)W_);
    float py = pixcoord(iy, (float)H_);
    float tx_hi = pixcoord(blockIdx.x*TILE,          (float)W_);
    float tx_lo = pixcoord(blockIdx.x*TILE + TILE-1, (float)W_);
    float ty_hi = pixcoord(blockIdx.y*TILE,          (float)H_);
    float ty_lo = pixcoord(blockIdx.y*TILE + TILE-1, (float)H_);
    int lane = tid & 63, wv = tid >> 6;
    int alive = *cnt;
    int nch = (alive + RCH-1) >> 8;

    float zbest = INFINITY, zskip = INFINITY;
    int fbest = -1, lastpub = -1;

    for (int c = blockIdx.z; c < nch; c += NS){
        // refresh conservative skip-depth from global keys (cross-slice sharing)
        ull kk = __hip_atomic_load(&keys[pix], __ATOMIC_RELAXED, __HIP_MEMORY_SCOPE_AGENT);
        zskip = fminf(zskip, __uint_as_float((unsigned)(kk >> 32)));
        // sound early exit: every remaining face has zmin >= sufchunk[c],
        // so zp >= zmin*(1-1e-6) > zskip strictly -> cannot win or tie
        int done = (xm(sufchunk[c], 0.999f) >= zskip) ? 1 : 0;
        if (__syncthreads_and(done)) break;   // barrier also protects lf reuse

        int f = (c << 8) + tid;
        bool keep = false;
        float4 q0, q1, q2, q3;
        if (f < alive){
            const float4* g = (const float4*)(srec + (size_t)f*16);
            q0 = g[0]; q1 = g[1]; q2 = g[2]; q3 = g[3];
            keep = (q3.x <= tx_hi) && (q3.y >= tx_lo) && (q3.z <= ty_hi) && (q3.w >= ty_lo);
        }
        ull m = __ballot(keep);
        if (lane == 0) wcnt[wv] = __popcll(m);
        __syncthreads();
        int basec = 0;
        #pragma unroll
        for (int w2 = 0; w2 < 4; ++w2) if (w2 < wv) basec += wcnt[w2];
        if (keep){
            int pos = basec + __popcll(m & ((1ULL << lane) - 1ULL));
            float4* l = (float4*)(lf + pos*16);
            l[0] = q0; l[1] = q1; l[2] = q2; l[3] = q3;
        }
        int nsurv = wcnt[0] + wcnt[1] + wcnt[2] + wcnt[3];
        __syncthreads();

        for (int k = 0; k < nsurv; k++){
            const float* r = lf + k*16;     // all lanes same addr -> LDS broadcast
            float t = xm(r[10], 0.999f);    // conservative zmin precheck
            if (t < zskip){
                // per-pixel bbox precheck (kills never-covered pixels cheaply)
                if (px >= r[12] && px <= r[13] && py >= r[14] && py <= r[15]){
                    float x0=r[0], y0=r[1], x1=r[2], y1=r[3], x2=r[4], y2=r[5];
                    float dx0=xsb(x0,px), dx1=xsb(x1,px), dx2=xsb(x2,px);
                    float dy0=xsb(y0,py), dy1=xsb(y1,py), dy2=xsb(y2,py);
                    float e0 = xsb(xm(dx1,dy2), xm(dy1,dx2));
                    float e1 = xsb(xm(dx2,dy0), xm(dy2,dx0));
                    float e2 = xsb(xm(dx0,dy1), xm(dy0,dx1));
                    if (e0 >= 0.f && e1 >= 0.f && e2 >= 0.f){
                        float z0=r[6], z1=r[7], z2=r[8], ia=r[9];
                        float w0 = xm(e0, ia), w1 = xm(e1, ia), w2 = xm(e2, ia);
                        float l0 = xm(xm(w0,z1),z2);
                        float l1 = xm(xm(z0,w1),z2);
                        float l2 = xm(xm(z0,z1),w2);
                        float s  = xa(xa(l0,l1),l2);
                        float dn = (s == 0.f) ? 1.0f : s;
                        float b0 = fmaxf(xd(l0,dn), 0.f);
                        float b1 = fmaxf(xd(l1,dn), 0.f);
                        float b2 = fmaxf(xd(l2,dn), 0.f);
                        float bs = fmaxf(xa(xa(b0,b1),b2), EPS_F);
                        b0 = xd(b0,bs); b1 = xd(b1,bs); b2 = xd(b2,bs);
                        float zp = xa(xa(xm(b0,z0),xm(b1,z1)),xm(b2,z2));
                        int fidx = __float_as_int(r[11]);
                        if (zp < zbest || (zp == zbest && fidx < fbest)){
                            zbest = zp; fbest = fidx;
                            zskip = fminf(zskip, zp);
                        }
                    }
                }
            }
        }
        // publish improvements so the sibling slice can skip
        if (fbest >= 0 && fbest != lastpub){
            ull key = (((ull)__float_as_uint(zbest)) << 32) | (unsigned)fbest;
            atomicMin(&keys[pix], key);
            lastpub = fbest;
        }
    }
}

// ---- kernel 7: fused resolve + shade (64 lanes/pixel = channels) ----
__global__ __launch_bounds__(256) void k_post(const ull* __restrict__ keys,
        const float* __restrict__ verts, const float* __restrict__ feats,
        const int* __restrict__ faces, float* __restrict__ out){
    int grp = threadIdx.x >> 6;
    int c = threadIdx.x & 63;
    int pix = blockIdx.x*4 + grp;
    float* p2f  = out + OFF_P2F;
    float* zbuf = out + OFF_ZBUF;
    float* bary = out + OFF_BARY;
    float* dist = out + OFF_DIST;
    ull key = keys[pix];
    if (key == 0xFFFFFFFFFFFFFFFFULL){
        out[OFF_FEATS + pix*C_ + c] = 0.0f;
        if (c == 0){ p2f[pix] = -1.0f; zbuf[pix] = -1.0f; dist[pix] = -1.0f; }
        if (c < 3) bary[3*pix+c] = -1.0f;
        return;
    }
    int f = (int)(key & 0xFFFFFFFFu);
    float z = __uint_as_float((unsigned)(key >> 32));
    int ix = pix % W_, iy = pix / W_;
    float px = pixcoord(ix, (float)W_);
    float py = pixcoord(iy, (float)H_);
    int i0 = faces[3*f+0], i1 = faces[3*f+1], i2 = faces[3*f+2];
    float x0=verts[4*i0+0], y0=verts[4*i0+1], z0=verts[4*i0+2];
    float x1=verts[4*i1+0], y1=verts[4*i1+1], z1=verts[4*i1+2];
    float x2=verts[4*i2+0], y2=verts[4*i2+1], z2=verts[4*i2+2];
    float area = xsb(xm(xsb(x1,x0), xsb(y2,y0)), xm(xsb(y1,y0), xsb(x2,x0)));
    float ia = xd(1.0f, area);   // winner is guaranteed a live face
    float w0 = xm(xsb(xm(xsb(x1,px),xsb(y2,py)), xm(xsb(y1,py),xsb(x2,px))), ia);
    float w1 = xm(xsb(xm(xsb(x2,px),xsb(y0,py)), xm(xsb(y2,py),xsb(x0,px))), ia);
    float w2 = xm(xsb(xm(xsb(x0,px),xsb(y1,py)), xm(xsb(y0,py),xsb(x1,px))), ia);
    float l0 = xm(xm(w0,z1),z2);
    float l1 = xm(xm(z0,w1),z2);
    float l2 = xm(xm(z0,z1),w2);
    float s  = xa(xa(l0,l1),l2);
    float dn = (s == 0.f) ? 1.0f : s;
    float b0 = fmaxf(xd(l0,dn), 0.f);
    float b1 = fmaxf(xd(l1,dn), 0.f);
    float b2 = fmaxf(xd(l2,dn), 0.f);
    float bs = fmaxf(xa(xa(b0,b1),b2), EPS_F);
    b0 = xd(b0,bs); b1 = xd(b1,bs); b2 = xd(b2,bs);
    float res = xa(xa(xm(b0, feats[i0*C_ + c]), xm(b1, feats[i1*C_ + c])),
                   xm(b2, feats[i2*C_ + c]));
    out[OFF_FEATS + pix*C_ + c] = res;
    if (c == 0){ p2f[pix] = (float)f; zbuf[pix] = z; dist[pix] = 0.0f; }
    if (c < 3){
        float bb = (c == 0) ? b0 : ((c == 1) ? b1 : b2);
        bary[3*pix+c] = bb;
    }
}

extern "C" void kernel_launch(void* const* d_in, const int* in_sizes, int n_in,
                              void* d_out, int out_size, void* d_ws, size_t ws_size,
                              hipStream_t stream) {
    const float* positions = (const float*)d_in[0];
    const float* features  = (const float*)d_in[1];
    const int*   faces     = (const int*)  d_in[2];
    const float* K         = (const float*)d_in[3];
    const float* RT        = (const float*)d_in[4];
    int V  = in_sizes[0] / 3;   // 8192
    int Fn = in_sizes[2] / 3;   // 16384

    float* verts    = (float*)d_ws;                       // V*4 floats
    float* srec     = verts + (size_t)V*4;                // Fn*16 floats (sorted records)
    ull*   keys     = (ull*)(srec + (size_t)Fn*16);       // H*W keys (8B-aligned)
    int*   cnt      = (int*)(keys + (size_t)H_*W_);
    int*   hist     = cnt + 1;                            // 256
    int*   cursor   = hist + NBUCK;                       // 256
    float* sufchunk = (float*)(cursor + NBUCK);           // 65

    int initN = H_*W_;  // covers keys (36864), verts (8192), hist (256)
    k_init   <<<(initN+255)/256, 256, 0, stream>>>(positions, K, RT, verts, keys, hist, V);
    k_hist   <<<(Fn+255)/256, 256, 0, stream>>>(faces, verts, hist, Fn);
    k_prefix <<<1, 256, 0, stream>>>(hist, cursor, cnt);
    k_scatter<<<(Fn+255)/256, 256, 0, stream>>>(faces, verts, cursor, srec, Fn);
    k_sufmin <<<1, 256, 0, stream>>>(srec, cnt, sufchunk);
    dim3 rg(W_/TILE, H_/TILE, NS);
    k_raster <<<rg, 256, 0, stream>>>(srec, cnt, sufchunk, keys);
    k_post   <<<(H_*W_)/4, 256, 0, stream>>>(keys, verts, features, faces, (float*)d_out);
}

// Round 5
// 200.732 us; speedup vs baseline: 2.0469x; 2.0469x over previous
//
#include <hip/hip_runtime.h>
#include <stdint.h>

#define H_ 192
#define W_ 192
#define C_ 64
#define EPS_F 1e-8f
#define TILE 16
#define RCH 256      // faces per raster chunk
#define NSLICE 16    // z-interleaved slices per tile
#define NBUCK 256
#define MAXCH 64     // max chunks (16384/256)

typedef unsigned long long ull;

// Output layout (floats), concatenated in reference return order:
// feats (H*W*C) | p2f (H*W) | zbuf (H*W) | bary (H*W*3) | dists (H*W)
#define OFF_FEATS 0
#define OFF_P2F   (H_*W_*C_)
#define OFF_ZBUF  (OFF_P2F + H_*W_)
#define OFF_BARY  (OFF_ZBUF + H_*W_)
#define OFF_DIST  (OFF_BARY + H_*W_*3)

// IEEE-exact ops (block FMA contraction; match numpy float32 op-for-op)
__device__ __forceinline__ float xm(float a, float b){ return __fmul_rn(a,b); }
__device__ __forceinline__ float xa(float a, float b){ return __fadd_rn(a,b); }
__device__ __forceinline__ float xsb(float a, float b){ return __fsub_rn(a,b); }
__device__ __forceinline__ float xd(float a, float b){ return __fdiv_rn(a,b); }

__device__ __forceinline__ float pixcoord(int i, float dim){
    float t = xa(xm(2.0f, (float)i), 1.0f);
    return xsb(1.0f, xd(t, dim));
}

__device__ __forceinline__ int zbucket(float zmn){
    int b = (int)((zmn - 2.5f) * 128.0f);   // scene z in [2.5,4.5); clamp keeps soundness
    return max(0, min(NBUCK-1, b));
}
// sound lower bound on zmin for any face in bucket >= b (bucket 0 -> 0 since z>0 enforced)
__device__ __forceinline__ float bucket_lb(int b){
    return (b == 0) ? 0.0f : (2.5f + (float)b * 0.0078125f);
}

// ---- kernel 1: keys init + hist/hist2 zero + vertex transform ----
__global__ void k_init(const float* __restrict__ pos, const float* __restrict__ K,
                       const float* __restrict__ RT, float* __restrict__ verts,
                       ull* __restrict__ keys, int* __restrict__ hist,
                       int* __restrict__ hist2, int V){
    int i = blockIdx.x*blockDim.x + threadIdx.x;
    if (i < NBUCK){ hist[i] = 0; hist2[i] = 0; }
    if (i < H_*W_) keys[i] = 0xFFFFFFFFFFFFFFFFULL;
    if (i >= V) return;
    float p0 = pos[3*i+0], p1 = pos[3*i+1], p2 = pos[3*i+2];
    const float sgn[3] = {-1.f, -1.f, 1.f};
    float vv[3];
    #pragma unroll
    for (int j=0;j<3;j++){
        float rp0 = xm(RT[j*4+0], sgn[j]);
        float rp1 = xm(RT[j*4+1], sgn[j]);
        float rp2 = xm(RT[j*4+2], sgn[j]);
        float s = xa(xa(xm(p0,rp0), xm(p1,rp1)), xm(p2,rp2));
        vv[j] = xa(s, xm(RT[j*4+3], sgn[j]));
    }
    float z = vv[2];
    const float scale = 96.0f;
    float fx = xd(K[0], scale);
    float fy = xd(K[4], scale);
    float p0x = -xd(xsb(K[2], 96.0f), scale);
    float p0y = -xd(xsb(K[5], 96.0f), scale);
    float xn = xa(xd(xm(fx, vv[0]), z), p0x);
    float yn = xa(xd(xm(fy, vv[1]), z), p0y);
    verts[4*i+0] = xn; verts[4*i+1] = yn; verts[4*i+2] = z; verts[4*i+3] = 0.f;
}

// ---- kernel 2: live-face zmin histogram (LDS-aggregated) ----
__global__ __launch_bounds__(256) void k_hist(const int* __restrict__ faces,
        const float* __restrict__ verts, int* __restrict__ hist, int Fn){
    __shared__ int lh[NBUCK];
    int t = threadIdx.x;
    lh[t] = 0;
    __syncthreads();
    int f = blockIdx.x*256 + t;
    if (f < Fn){
        int i0 = faces[3*f+0], i1 = faces[3*f+1], i2 = faces[3*f+2];
        float4 v0 = ((const float4*)verts)[i0];
        float4 v1 = ((const float4*)verts)[i1];
        float4 v2 = ((const float4*)verts)[i2];
        float area = xsb(xm(xsb(v1.x,v0.x), xsb(v2.y,v0.y)), xm(xsb(v1.y,v0.y), xsb(v2.x,v0.x)));
        bool ok = (area > EPS_F) && (v0.z > 0.f) && (v1.z > 0.f) && (v2.z > 0.f);
        if (ok){
            float zmn = fminf(v0.z, fminf(v1.z, v2.z));
            atomicAdd(&lh[zbucket(zmn)], 1);
        }
    }
    __syncthreads();
    if (lh[t]) atomicAdd(&hist[t], lh[t]);
}

// ---- kernel 3: scatter live faces into z-bucket-sorted records ----
// (each block recomputes the exclusive prefix of hist in LDS; within-bucket
//  slots come from the zeroed hist2 cursor array)
// record (16 floats): x0,y0,x1,y1 | x2,y2,z0,z1 | z2,ia,zmin,fidx(bits) | xmn,xmx,ymn,ymx
__global__ __launch_bounds__(256) void k_scatter(const int* __restrict__ faces,
        const float* __restrict__ verts, const int* __restrict__ hist,
        int* __restrict__ hist2, float* __restrict__ srec, int Fn){
    __shared__ int incl_s[NBUCK];
    int t = threadIdx.x;
    int h = hist[t];
    incl_s[t] = h;
    __syncthreads();
    for (int off=1; off<NBUCK; off<<=1){
        int u = (t >= off) ? incl_s[t-off] : 0;
        __syncthreads();
        incl_s[t] += u;
        __syncthreads();
    }
    int f = blockIdx.x*256 + t;
    if (f >= Fn) return;
    int i0 = faces[3*f+0], i1 = faces[3*f+1], i2 = faces[3*f+2];
    float4 v0 = ((const float4*)verts)[i0];
    float4 v1 = ((const float4*)verts)[i1];
    float4 v2 = ((const float4*)verts)[i2];
    float area = xsb(xm(xsb(v1.x,v0.x), xsb(v2.y,v0.y)), xm(xsb(v1.y,v0.y), xsb(v2.x,v0.x)));
    bool ok = (area > EPS_F) && (v0.z > 0.f) && (v1.z > 0.f) && (v2.z > 0.f);
    if (!ok) return;
    float zmn = fminf(v0.z, fminf(v1.z, v2.z));
    int b = zbucket(zmn);
    int excl = incl_s[b] - hist[b];
    int pos = excl + atomicAdd(&hist2[b], 1);
    if (pos >= Fn) return;   // safety (pristine inputs never hit this)
    float ia = xd(1.0f, area);
    float xmn = fminf(v0.x, fminf(v1.x, v2.x)) - 1e-4f;
    float xmx = fmaxf(v0.x, fmaxf(v1.x, v2.x)) + 1e-4f;
    float ymn = fminf(v0.y, fminf(v1.y, v2.y)) - 1e-4f;
    float ymx = fmaxf(v0.y, fmaxf(v1.y, v2.y)) + 1e-4f;
    float4* q = (float4*)(srec + (size_t)pos*16);
    q[0] = make_float4(v0.x, v0.y, v1.x, v1.y);
    q[1] = make_float4(v2.x, v2.y, v0.z, v1.z);
    q[2] = make_float4(v2.z, ia, zmn, __int_as_float(f));
    q[3] = make_float4(xmn, xmx, ymn, ymx);
}

// ---- kernel 4: z-ordered tiled raster, 2304 blocks, per-pixel early-out ----
__global__ __launch_bounds__(256) void k_raster(const float* __restrict__ srec,
        const int* __restrict__ hist, ull* __restrict__ keys, int Fn){
    __shared__ float lf[RCH*16];      // staged face records
    __shared__ int   incl_s[NBUCK];   // inclusive prefix of hist
    __shared__ float chunk_lb[MAXCH]; // sound zmin lower bound for positions >= c*256
    __shared__ int   wcnt[4];
    int tid = threadIdx.x;

    // per-block prefix of hist -> alive count + analytic chunk lower bounds
    incl_s[tid] = hist[tid];
    __syncthreads();
    for (int off=1; off<NBUCK; off<<=1){
        int u = (tid >= off) ? incl_s[tid-off] : 0;
        __syncthreads();
        incl_s[tid] += u;
        __syncthreads();
    }
    int alive = min(max(incl_s[NBUCK-1], 0), Fn);   // clamp: robust to replay garbage
    if (tid < MAXCH){
        int p = tid << 8;
        int lo = 0, hi = NBUCK-1;     // smallest bucket with incl > p
        while (lo < hi){ int mid = (lo+hi) >> 1; if (incl_s[mid] > p) hi = mid; else lo = mid+1; }
        chunk_lb[tid] = bucket_lb(lo);
    }
    __syncthreads();

    int ix = blockIdx.x*TILE + (tid & 15);
    int iy = blockIdx.y*TILE + (tid >> 4);
    int pix = iy*W_ + ix;
    float px = pixcoord(ix, (float)W_);
    float py = pixcoord(iy, (float)H_);
    float tx_hi = pixcoord(blockIdx.x*TILE,          (float)W_);
    float tx_lo = pixcoord(blockIdx.x*TILE + TILE-1, (float)W_);
    float ty_hi = pixcoord(blockIdx.y*TILE,          (float)H_);
    float ty_lo = pixcoord(blockIdx.y*TILE + TILE-1, (float)H_);
    int lane = tid & 63, wv = tid >> 6;
    int nch = min((alive + RCH-1) >> 8, MAXCH);

    float zbest = INFINITY, zskip = INFINITY;
    int fbest = -1, lastpub = -1;

    for (int c = blockIdx.z; c < nch; c += NSLICE){
        // refresh conservative skip-depth from global keys (cross-slice sharing)
        ull kk = __hip_atomic_load(&keys[pix], __ATOMIC_RELAXED, __HIP_MEMORY_SCOPE_AGENT);
        zskip = fminf(zskip, __uint_as_float((unsigned)(kk >> 32)));
        // sound block-wide exit: remaining faces have zmin >= chunk_lb[c],
        // so zp > zmin*0.999 >= zskip strictly -> cannot win or tie
        int done = (xm(chunk_lb[c], 0.999f) >= zskip) ? 1 : 0;
        if (__syncthreads_and(done)) break;   // barrier also protects lf reuse

        int f = (c << 8) + tid;
        bool keep = false;
        float4 q0, q1, q2, q3;
        if (f < alive){
            const float4* g = (const float4*)(srec + (size_t)f*16);
            q0 = g[0]; q1 = g[1]; q2 = g[2]; q3 = g[3];
            keep = (q3.x <= tx_hi) && (q3.y >= tx_lo) && (q3.z <= ty_hi) && (q3.w >= ty_lo);
        }
        ull m = __ballot(keep);
        if (lane == 0) wcnt[wv] = __popcll(m);
        __syncthreads();
        int basec = 0;
        #pragma unroll
        for (int w2 = 0; w2 < 4; ++w2) if (w2 < wv) basec += wcnt[w2];
        if (keep){
            int pos = basec + __popcll(m & ((1ULL << lane) - 1ULL));
            float4* l = (float4*)(lf + pos*16);
            l[0] = q0; l[1] = q1; l[2] = q2; l[3] = q3;
        }
        int nsurv = wcnt[0] + wcnt[1] + wcnt[2] + wcnt[3];
        __syncthreads();

        for (int k = 0; k < nsurv; k++){
            const float* r = lf + k*16;        // same addr all lanes -> LDS broadcast
            float t = xm(r[10], 0.999f);       // conservative zmin precheck (dominant kill)
            if (t >= zskip) continue;
            // per-pixel bbox precheck (kills never-covered pixels cheaply)
            if (px < r[12] || px > r[13] || py < r[14] || py > r[15]) continue;
            float x0=r[0], y0=r[1], x1=r[2], y1=r[3], x2=r[4], y2=r[5];
            float dx0=xsb(x0,px), dx1=xsb(x1,px), dx2=xsb(x2,px);
            float dy0=xsb(y0,py), dy1=xsb(y1,py), dy2=xsb(y2,py);
            float e0 = xsb(xm(dx1,dy2), xm(dy1,dx2));
            float e1 = xsb(xm(dx2,dy0), xm(dy2,dx0));
            float e2 = xsb(xm(dx0,dy1), xm(dy0,dx1));
            if (e0 >= 0.f && e1 >= 0.f && e2 >= 0.f){
                float z0=r[6], z1=r[7], z2=r[8], ia=r[9];
                float w0 = xm(e0, ia), w1 = xm(e1, ia), w2 = xm(e2, ia);
                float l0 = xm(xm(w0,z1),z2);
                float l1 = xm(xm(z0,w1),z2);
                float l2 = xm(xm(z0,z1),w2);
                float s  = xa(xa(l0,l1),l2);
                float dn = (s == 0.f) ? 1.0f : s;
                float b0 = fmaxf(xd(l0,dn), 0.f);
                float b1 = fmaxf(xd(l1,dn), 0.f);
                float b2 = fmaxf(xd(l2,dn), 0.f);
                float bs = fmaxf(xa(xa(b0,b1),b2), EPS_F);
                b0 = xd(b0,bs); b1 = xd(b1,bs); b2 = xd(b2,bs);
                float zp = xa(xa(xm(b0,z0),xm(b1,z1)),xm(b2,z2));
                int fidx = __float_as_int(r[11]);
                if (zp < zbest || (zp == zbest && fidx < fbest)){
                    zbest = zp; fbest = fidx;
                    zskip = fminf(zskip, zp);
                }
            }
        }
        // publish improvements so sibling slices can skip
        if (fbest >= 0 && fbest != lastpub){
            ull key = (((ull)__float_as_uint(zbest)) << 32) | (unsigned)fbest;
            atomicMin(&keys[pix], key);
            lastpub = fbest;
        }
    }
}

// ---- kernel 5: fused resolve + shade (64 lanes/pixel = channels) ----
__global__ __launch_bounds__(256) void k_post(const ull* __restrict__ keys,
        const float* __restrict__ verts, const float* __restrict__ feats,
        const int* __restrict__ faces, float* __restrict__ out){
    int grp = threadIdx.x >> 6;
    int c = threadIdx.x & 63;
    int pix = blockIdx.x*4 + grp;
    float* p2f  = out + OFF_P2F;
    float* zbuf = out + OFF_ZBUF;
    float* bary = out + OFF_BARY;
    float* dist = out + OFF_DIST;
    ull key = keys[pix];
    if (key == 0xFFFFFFFFFFFFFFFFULL){
        out[OFF_FEATS + pix*C_ + c] = 0.0f;
        if (c == 0){ p2f[pix] = -1.0f; zbuf[pix] = -1.0f; dist[pix] = -1.0f; }
        if (c < 3) bary[3*pix+c] = -1.0f;
        return;
    }
    int f = (int)(key & 0xFFFFFFFFu);
    float z = __uint_as_float((unsigned)(key >> 32));
    int ix = pix % W_, iy = pix / W_;
    float px = pixcoord(ix, (float)W_);
    float py = pixcoord(iy, (float)H_);
    int i0 = faces[3*f+0], i1 = faces[3*f+1], i2 = faces[3*f+2];
    float x0=verts[4*i0+0], y0=verts[4*i0+1], z0=verts[4*i0+2];
    float x1=verts[4*i1+0], y1=verts[4*i1+1], z1=verts[4*i1+2];
    float x2=verts[4*i2+0], y2=verts[4*i2+1], z2=verts[4*i2+2];
    float area = xsb(xm(xsb(x1,x0), xsb(y2,y0)), xm(xsb(y1,y0), xsb(x2,x0)));
    float ia = xd(1.0f, area);   // winner is guaranteed a live face
    float w0 = xm(xsb(xm(xsb(x1,px),xsb(y2,py)), xm(xsb(y1,py),xsb(x2,px))), ia);
    float w1 = xm(xsb(xm(xsb(x2,px),xsb(y0,py)), xm(xsb(y2,py),xsb(x0,px))), ia);
    float w2 = xm(xsb(xm(xsb(x0,px),xsb(y1,py)), xm(xsb(y0,py),xsb(x1,px))), ia);
    float l0 = xm(xm(w0,z1),z2);
    float l1 = xm(xm(z0,w1),z2);
    float l2 = xm(xm(z0,z1),w2);
    float s  = xa(xa(l0,l1),l2);
    float dn = (s == 0.f) ? 1.0f : s;
    float b0 = fmaxf(xd(l0,dn), 0.f);
    float b1 = fmaxf(xd(l1,dn), 0.f);
    float b2 = fmaxf(xd(l2,dn), 0.f);
    float bs = fmaxf(xa(xa(b0,b1),b2), EPS_F);
    b0 = xd(b0,bs); b1 = xd(b1,bs); b2 = xd(b2,bs);
    float res = xa(xa(xm(b0, feats[i0*C_ + c]), xm(b1, feats[i1*C_ + c])),
                   xm(b2, feats[i2*C_ + c]));
    out[OFF_FEATS + pix*C_ + c] = res;
    if (c == 0){ p2f[pix] = (float)f; zbuf[pix] = z; dist[pix] = 0.0f; }
    if (c < 3){
        float bb = (c == 0) ? b0 : ((c == 1) ? b1 : b2);
        bary[3*pix+c] = bb;
    }
}

extern "C" void kernel_launch(void* const* d_in, const int* in_sizes, int n_in,
                              void* d_out, int out_size, void* d_ws, size_t ws_size,
                              hipStream_t stream) {
    const float* positions = (const float*)d_in[0];
    const float* features  = (const float*)d_in[1];
    const int*   faces     = (const int*)  d_in[2];
    const float* K         = (const float*)d_in[3];
    const float* RT        = (const float*)d_in[4];
    int V  = in_sizes[0] / 3;   // 8192
    int Fn = in_sizes[2] / 3;   // 16384

    float* verts = (float*)d_ws;                     // V*4 floats
    float* srec  = verts + (size_t)V*4;              // Fn*16 floats (sorted records)
    ull*   keys  = (ull*)(srec + (size_t)Fn*16);     // H*W keys (8B-aligned)
    int*   hist  = (int*)(keys + (size_t)H_*W_);     // 256
    int*   hist2 = hist + NBUCK;                     // 256 (scatter cursors)

    int initN = H_*W_;  // covers keys (36864), verts (8192), hist/hist2 (256)
    k_init   <<<(initN+255)/256, 256, 0, stream>>>(positions, K, RT, verts, keys, hist, hist2, V);
    k_hist   <<<(Fn+255)/256, 256, 0, stream>>>(faces, verts, hist, Fn);
    k_scatter<<<(Fn+255)/256, 256, 0, stream>>>(faces, verts, hist, hist2, srec, Fn);
    dim3 rg(W_/TILE, H_/TILE, NSLICE);
    k_raster <<<rg, 256, 0, stream>>>(srec, hist, keys, Fn);
    k_post   <<<(H_*W_)/4, 256, 0, stream>>>(keys, verts, features, faces, (float*)d_out);
}